// Round 1
// baseline (489.424 us; speedup 1.0000x reference)
//
#include <hip/hip_runtime.h>
#include <hip/hip_bf16.h>
#include <math.h>

#define B_ROWS 8192
#define DDIM   1024
#define NEXP   8

typedef __attribute__((ext_vector_type(8))) __bf16 bf16x8;
typedef __attribute__((ext_vector_type(4))) float  f32x4;

__device__ __forceinline__ unsigned short f2bf(float f) {
    // round-to-nearest-even f32 -> bf16
    unsigned u = __builtin_bit_cast(unsigned, f);
    u = (u + 0x7fffu + ((u >> 16) & 1u)) >> 16;
    return (unsigned short)u;
}

// ---------------------------------------------------------------------------
// Kernel 1: gating. One wave per row, 4 rows per 256-thread block.
// f64 accumulation so top-k selection matches the f64 numpy reference.
// Emits per-expert row lists + gate weights via atomic counters.
// ---------------------------------------------------------------------------
__global__ __launch_bounds__(256) void gating_kernel(
    const float* __restrict__ x, const float* __restrict__ noise,
    const float* __restrict__ w_gate, const float* __restrict__ w_noise,
    int* __restrict__ counts, int* __restrict__ rowlist, float* __restrict__ gatelist)
{
    const int t    = threadIdx.x;
    const int wave = t >> 6;
    const int lane = t & 63;
    const int b    = blockIdx.x * 4 + wave;

    double accg[NEXP], accn[NEXP];
#pragma unroll
    for (int e = 0; e < NEXP; ++e) { accg[e] = 0.0; accn[e] = 0.0; }

    const float* xr = x + (size_t)b * DDIM;
#pragma unroll 4
    for (int i = 0; i < DDIM / 64; ++i) {
        const int d = i * 64 + lane;
        const double xd = (double)xr[d];
        const float4* wg = (const float4*)(w_gate  + (size_t)d * NEXP);
        const float4* wn = (const float4*)(w_noise + (size_t)d * NEXP);
        float4 g0 = wg[0], g1 = wg[1];
        float4 n0 = wn[0], n1 = wn[1];
        accg[0] += xd * (double)g0.x; accg[1] += xd * (double)g0.y;
        accg[2] += xd * (double)g0.z; accg[3] += xd * (double)g0.w;
        accg[4] += xd * (double)g1.x; accg[5] += xd * (double)g1.y;
        accg[6] += xd * (double)g1.z; accg[7] += xd * (double)g1.w;
        accn[0] += xd * (double)n0.x; accn[1] += xd * (double)n0.y;
        accn[2] += xd * (double)n0.z; accn[3] += xd * (double)n0.w;
        accn[4] += xd * (double)n1.x; accn[5] += xd * (double)n1.y;
        accn[6] += xd * (double)n1.z; accn[7] += xd * (double)n1.w;
    }

    // 64-lane butterfly reduction (doubles shuffle as 2x32b)
#pragma unroll
    for (int off = 32; off > 0; off >>= 1) {
#pragma unroll
        for (int e = 0; e < NEXP; ++e) {
            accg[e] += __shfl_xor(accg[e], off);
            accn[e] += __shfl_xor(accn[e], off);
        }
    }

    if (lane == 0) {
        double lg[NEXP];
#pragma unroll
        for (int e = 0; e < NEXP; ++e) {
            const double z  = accn[e];
            const double sp = (z > 30.0) ? z : log1p(exp(z));       // softplus
            lg[e] = accg[e] + (double)noise[(size_t)b * NEXP + e] * (sp + 0.01);
        }
        // top-2, ties -> lower index (matches jax.lax.top_k)
        int i0 = 0; double l0 = lg[0];
#pragma unroll
        for (int e = 1; e < NEXP; ++e) if (lg[e] > l0) { l0 = lg[e]; i0 = e; }
        int i1 = -1; double l1 = -1.0e300;
#pragma unroll
        for (int e = 0; e < NEXP; ++e) if (e != i0 && lg[e] > l1) { l1 = lg[e]; i1 = e; }
        const double g0 = 1.0 / (1.0 + exp(l1 - l0));   // softmax over {l0,l1}, l1<=l0
        const double g1 = 1.0 - g0;

        int p0 = atomicAdd(&counts[i0], 1);
        rowlist [i0 * B_ROWS + p0] = b;
        gatelist[i0 * B_ROWS + p0] = (float)g0;
        int p1 = atomicAdd(&counts[i1], 1);
        rowlist [i1 * B_ROWS + p1] = b;
        gatelist[i1 * B_ROWS + p1] = (float)g1;
    }
}

// ---------------------------------------------------------------------------
// Kernel 2: grouped expert GEMM, bf16 MFMA 16x16x32, 128x128 tile, BK=64.
// A = gathered x rows (f32 -> bf16 reg-staged), B = W_experts[e] staged
// TRANSPOSED ([n][k]) via per-thread k-gather so frags are ds_read_b128.
// XOR swizzle ((row&7)<<4) on 16B columns kills the 128B-stride conflicts.
// Epilogue: out[b,h] += gate * exp(acc + bias[e,h])  (f32 atomic add).
// ---------------------------------------------------------------------------
__global__ __launch_bounds__(256) void moe_gemm_kernel(
    const float* __restrict__ x, const float* __restrict__ W,
    const float* __restrict__ bias,
    const int* __restrict__ counts, const int* __restrict__ rowlist,
    const float* __restrict__ gatelist, float* __restrict__ out)
{
    const int e  = blockIdx.z;
    const int mt = blockIdx.y;
    const int nt = blockIdx.x;
    const int cnt  = counts[e];
    const int row0 = mt * 128;
    if (row0 >= cnt) return;

    __shared__ int   srow[128];
    __shared__ float sgate[128];
    __shared__ __align__(16) unsigned char Alds[128 * 64 * 2];   // [row][k] bf16, swizzled
    __shared__ __align__(16) unsigned char Blds[128 * 64 * 2];   // [n][k]  bf16, swizzled

    const int t = threadIdx.x;
    if (t < 128) {
        const int r = row0 + t;
        if (r < cnt) { srow[t] = rowlist[e * B_ROWS + r]; sgate[t] = gatelist[e * B_ROWS + r]; }
        else         { srow[t] = 0;                       sgate[t] = 0.0f; }
    }
    __syncthreads();

    const int wave = t >> 6, lane = t & 63;
    const int wr = wave >> 1, wc = wave & 1;
    const int l4 = lane >> 4, l16 = lane & 15;

    f32x4 acc[4][4];
#pragma unroll
    for (int m = 0; m < 4; ++m)
#pragma unroll
        for (int n = 0; n < 4; ++n) acc[m][n] = (f32x4){0.f, 0.f, 0.f, 0.f};

    const float* We = W + (size_t)e * DDIM * DDIM + (size_t)nt * 128;

    for (int kt = 0; kt < DDIM / 64; ++kt) {
        // ---- stage A: 128 rows x 64 k (gathered x rows), f32->bf16 ----
#pragma unroll
        for (int c = 0; c < 4; ++c) {
            const int idx = t + c * 256;
            const int row = idx >> 3, k8 = idx & 7;           // 8 threads/row, 8 k-chunks
            const float* src = x + (size_t)srow[row] * DDIM + kt * 64 + k8 * 8;
            const float4 f0 = *(const float4*)src;
            const float4 f1 = *(const float4*)(src + 4);
            union { bf16x8 v; unsigned short u[8]; } pk;
            pk.u[0] = f2bf(f0.x); pk.u[1] = f2bf(f0.y); pk.u[2] = f2bf(f0.z); pk.u[3] = f2bf(f0.w);
            pk.u[4] = f2bf(f1.x); pk.u[5] = f2bf(f1.y); pk.u[6] = f2bf(f1.z); pk.u[7] = f2bf(f1.w);
            *(bf16x8*)(Alds + row * 128 + ((k8 * 16) ^ ((row & 7) << 4))) = pk.v;
        }
        // ---- stage B: W[e][k][n] -> Blds[n][k] (transpose via k-gather) ----
#pragma unroll
        for (int c = 0; c < 4; ++c) {
            const int idx = t + c * 256;
            const int n = idx & 127, kc = idx >> 7;           // kc in 0..7
            const float* src = We + (size_t)(kt * 64 + kc * 8) * DDIM + n;
            union { bf16x8 v; unsigned short u[8]; } pk;
#pragma unroll
            for (int j = 0; j < 8; ++j) pk.u[j] = f2bf(src[(size_t)j * DDIM]);
            *(bf16x8*)(Blds + n * 128 + ((kc * 16) ^ ((n & 7) << 4))) = pk.v;
        }
        __syncthreads();

        // ---- compute: 2 x (4x4) MFMA 16x16x32 ----
#pragma unroll
        for (int ks = 0; ks < 2; ++ks) {
            bf16x8 af[4], bf[4];
#pragma unroll
            for (int m = 0; m < 4; ++m) {
                const int row = wr * 64 + m * 16 + l16;
                af[m] = *(const bf16x8*)(Alds + row * 128 + ((ks * 64 + l4 * 16) ^ ((row & 7) << 4)));
            }
#pragma unroll
            for (int n = 0; n < 4; ++n) {
                const int rn = wc * 64 + n * 16 + l16;
                bf[n] = *(const bf16x8*)(Blds + rn * 128 + ((ks * 64 + l4 * 16) ^ ((rn & 7) << 4)));
            }
#pragma unroll
            for (int m = 0; m < 4; ++m)
#pragma unroll
                for (int n = 0; n < 4; ++n)
                    acc[m][n] = __builtin_amdgcn_mfma_f32_16x16x32_bf16(af[m], bf[n], acc[m][n], 0, 0, 0);
        }
        __syncthreads();
    }

    // ---- epilogue: out[b,h] += g * exp(acc + bias) ----
#pragma unroll
    for (int m = 0; m < 4; ++m) {
#pragma unroll
        for (int n = 0; n < 4; ++n) {
#pragma unroll
            for (int j = 0; j < 4; ++j) {
                const int R = wr * 64 + m * 16 + l4 * 4 + j;   // C/D: row=(l>>4)*4+j, col=l&15
                if (row0 + R < cnt) {
                    const int   brow = srow[R];
                    const float g    = sgate[R];
                    const int   h    = nt * 128 + wc * 64 + n * 16 + l16;
                    const float v    = g * __expf(acc[m][n][j] + bias[e * DDIM + h]);
                    unsafeAtomicAdd(out + (size_t)brow * DDIM + h, v);
                }
            }
        }
    }
}

// ---------------------------------------------------------------------------
// Kernel 3: in-place out = log(max(combined, EPS-on-zero))
// ---------------------------------------------------------------------------
__global__ __launch_bounds__(256) void logeps_kernel(float* __restrict__ o, int n4)
{
    const float EPSF = 2.220446049250313e-16f;  // np.finfo(float64).eps
    int i = blockIdx.x * blockDim.x + threadIdx.x;
    const int stride = gridDim.x * blockDim.x;
    float4* p = (float4*)o;
    for (; i < n4; i += stride) {
        float4 v = p[i];
        v.x = __logf(v.x == 0.0f ? EPSF : v.x);
        v.y = __logf(v.y == 0.0f ? EPSF : v.y);
        v.z = __logf(v.z == 0.0f ? EPSF : v.z);
        v.w = __logf(v.w == 0.0f ? EPSF : v.w);
        p[i] = v;
    }
}

// ---------------------------------------------------------------------------
extern "C" void kernel_launch(void* const* d_in, const int* in_sizes, int n_in,
                              void* d_out, int out_size, void* d_ws, size_t ws_size,
                              hipStream_t stream)
{
    const float* x       = (const float*)d_in[0];
    const float* noise   = (const float*)d_in[1];
    const float* w_gate  = (const float*)d_in[2];
    const float* w_noise = (const float*)d_in[3];
    const float* W       = (const float*)d_in[4];
    const float* bias    = (const float*)d_in[5];
    float* out = (float*)d_out;

    char* ws = (char*)d_ws;
    int*   counts   = (int*)ws;                                   // 8 ints
    int*   rowlist  = (int*)(ws + 64);                            // 8 x 8192 ints
    float* gatelist = (float*)(ws + 64 + NEXP * B_ROWS * 4);      // 8 x 8192 floats

    hipMemsetAsync(counts, 0, 64, stream);
    hipMemsetAsync(d_out, 0, (size_t)out_size * sizeof(float), stream);

    gating_kernel<<<B_ROWS / 4, 256, 0, stream>>>(x, noise, w_gate, w_noise,
                                                  counts, rowlist, gatelist);

    dim3 grid(NEXP, B_ROWS / 128, NEXP);   // (nt=8, mt=64 worst case, e=8)
    moe_gemm_kernel<<<grid, 256, 0, stream>>>(x, W, bias, counts, rowlist, gatelist, out);

    logeps_kernel<<<2048, 256, 0, stream>>>(out, out_size / 4);
}

// Round 2
// 396.014 us; speedup vs baseline: 1.2359x; 1.2359x over previous
//
#include <hip/hip_runtime.h>
#include <hip/hip_bf16.h>
#include <math.h>

#define B_ROWS 8192
#define DDIM   1024
#define NEXP   8

typedef __attribute__((ext_vector_type(8))) __bf16 bf16x8;
typedef __attribute__((ext_vector_type(4))) float  f32x4;

__device__ __forceinline__ unsigned short f2bf(float f) {
    // round-to-nearest-even f32 -> bf16
    unsigned u = __builtin_bit_cast(unsigned, f);
    u = (u + 0x7fffu + ((u >> 16) & 1u)) >> 16;
    return (unsigned short)u;
}

// ---------------------------------------------------------------------------
// Kernel 1: gating, v2. Block = 512 threads covering 16 rows.
// Thread (kh, r, cg): kh = K-slice (1024/8=128 k), r = row-in-block,
// cg = column group (4 of the 16 logit columns: cg 0,1 -> w_gate cols 0-3,4-7;
// cg 2,3 -> w_noise cols 0-3,4-7).  f32 products, f64 accumulation: logit
// abs error ~4e-8 -> top-k selection matches the f64 numpy reference.
// Partials reduced through LDS; per-row top-2 via 8-lane shuffle butterfly
// (tie -> lower index, matching jax.lax.top_k).
// ---------------------------------------------------------------------------
__global__ __launch_bounds__(512) void gating_kernel(
    const float* __restrict__ x, const float* __restrict__ noise,
    const float* __restrict__ w_gate, const float* __restrict__ w_noise,
    int* __restrict__ counts, int* __restrict__ rowlist, float* __restrict__ gatelist)
{
    __shared__ double sacc[8][16][16];   // [kh][r][c]

    const int t  = threadIdx.x;
    const int kh = t >> 6;          // 0..7  (one wave per kh)
    const int r  = (t >> 2) & 15;   // 0..15
    const int cg = t & 3;           // 0..3
    const int b  = blockIdx.x * 16 + r;

    const float* wbase = (cg < 2) ? w_gate : w_noise;
    const float* wr    = wbase + (cg & 1) * 4;
    const float* xr    = x + (size_t)b * DDIM + kh * 128;

    double a0 = 0.0, a1 = 0.0, a2 = 0.0, a3 = 0.0;
#pragma unroll 4
    for (int k4 = 0; k4 < 32; ++k4) {
        const float4 xv = *(const float4*)(xr + k4 * 4);
        const float xs[4] = {xv.x, xv.y, xv.z, xv.w};
#pragma unroll
        for (int j = 0; j < 4; ++j) {
            const float4 wv = *(const float4*)(wr + (size_t)(kh * 128 + k4 * 4 + j) * NEXP);
            a0 += (double)(xs[j] * wv.x);
            a1 += (double)(xs[j] * wv.y);
            a2 += (double)(xs[j] * wv.z);
            a3 += (double)(xs[j] * wv.w);
        }
    }
    const int c0 = cg * 4;
    sacc[kh][r][c0 + 0] = a0;
    sacc[kh][r][c0 + 1] = a1;
    sacc[kh][r][c0 + 2] = a2;
    sacc[kh][r][c0 + 3] = a3;
    __syncthreads();

    if (t < 256) {
        const int rr = t >> 4;      // row in block (lane>>4 within wave)
        const int c  = t & 15;      // 0..7 clean logits, 8..15 noise-matvec
        const int bb = blockIdx.x * 16 + rr;

        double v = 0.0;
#pragma unroll
        for (int q = 0; q < 8; ++q) v += sacc[q][rr][c];

        const double vnoise = __shfl_xor(v, 8);   // partner column c^8

        double lgv = -1.0e300;
        if (c < 8) {
            const double z  = vnoise;
            const double sp = (z > 30.0) ? z : log1p(exp(z));
            lgv = v + (double)noise[(size_t)bb * NEXP + c] * (sp + 0.01);
        }

        // top-1 butterfly over the 8 logit lanes (xor 1,2,4 keeps groups closed)
        double bv = lgv; int bi = c;
#pragma unroll
        for (int off = 1; off <= 4; off <<= 1) {
            const double ov = __shfl_xor(bv, off);
            const int    oi = __shfl_xor(bi, off);
            if (ov > bv || (ov == bv && oi < bi)) { bv = ov; bi = oi; }
        }
        // top-2: mask the winner, reduce again
        double lg2 = (c == bi) ? -1.0e300 : lgv;
        double b2v = lg2; int b2i = c;
#pragma unroll
        for (int off = 1; off <= 4; off <<= 1) {
            const double ov = __shfl_xor(b2v, off);
            const int    oi = __shfl_xor(b2i, off);
            if (ov > b2v || (ov == b2v && oi < b2i)) { b2v = ov; b2i = oi; }
        }

        if (c == 0) {
            const double l0 = bv, l1 = b2v;
            const int    i0 = bi, i1 = b2i;
            const double g0 = 1.0 / (1.0 + exp(l1 - l0));   // softmax of {l0,l1}
            const double g1 = 1.0 - g0;

            int p0 = atomicAdd(&counts[i0], 1);
            rowlist [i0 * B_ROWS + p0] = bb;
            gatelist[i0 * B_ROWS + p0] = (float)g0;
            int p1 = atomicAdd(&counts[i1], 1);
            rowlist [i1 * B_ROWS + p1] = bb;
            gatelist[i1 * B_ROWS + p1] = (float)g1;
        }
    }
}

// ---------------------------------------------------------------------------
// Kernel 2: grouped expert GEMM, bf16 MFMA 16x16x32, 128x128 tile, BK=64.
// (unchanged from round 1)
// ---------------------------------------------------------------------------
__global__ __launch_bounds__(256) void moe_gemm_kernel(
    const float* __restrict__ x, const float* __restrict__ W,
    const float* __restrict__ bias,
    const int* __restrict__ counts, const int* __restrict__ rowlist,
    const float* __restrict__ gatelist, float* __restrict__ out)
{
    const int e  = blockIdx.z;
    const int mt = blockIdx.y;
    const int nt = blockIdx.x;
    const int cnt  = counts[e];
    const int row0 = mt * 128;
    if (row0 >= cnt) return;

    __shared__ int   srow[128];
    __shared__ float sgate[128];
    __shared__ __align__(16) unsigned char Alds[128 * 64 * 2];   // [row][k] bf16, swizzled
    __shared__ __align__(16) unsigned char Blds[128 * 64 * 2];   // [n][k]  bf16, swizzled

    const int t = threadIdx.x;
    if (t < 128) {
        const int r = row0 + t;
        if (r < cnt) { srow[t] = rowlist[e * B_ROWS + r]; sgate[t] = gatelist[e * B_ROWS + r]; }
        else         { srow[t] = 0;                       sgate[t] = 0.0f; }
    }
    __syncthreads();

    const int wave = t >> 6, lane = t & 63;
    const int wr = wave >> 1, wc = wave & 1;
    const int l4 = lane >> 4, l16 = lane & 15;

    f32x4 acc[4][4];
#pragma unroll
    for (int m = 0; m < 4; ++m)
#pragma unroll
        for (int n = 0; n < 4; ++n) acc[m][n] = (f32x4){0.f, 0.f, 0.f, 0.f};

    const float* We = W + (size_t)e * DDIM * DDIM + (size_t)nt * 128;

    for (int kt = 0; kt < DDIM / 64; ++kt) {
        // ---- stage A: 128 rows x 64 k (gathered x rows), f32->bf16 ----
#pragma unroll
        for (int c = 0; c < 4; ++c) {
            const int idx = t + c * 256;
            const int row = idx >> 3, k8 = idx & 7;           // 8 threads/row, 8 k-chunks
            const float* src = x + (size_t)srow[row] * DDIM + kt * 64 + k8 * 8;
            const float4 f0 = *(const float4*)src;
            const float4 f1 = *(const float4*)(src + 4);
            union { bf16x8 v; unsigned short u[8]; } pk;
            pk.u[0] = f2bf(f0.x); pk.u[1] = f2bf(f0.y); pk.u[2] = f2bf(f0.z); pk.u[3] = f2bf(f0.w);
            pk.u[4] = f2bf(f1.x); pk.u[5] = f2bf(f1.y); pk.u[6] = f2bf(f1.z); pk.u[7] = f2bf(f1.w);
            *(bf16x8*)(Alds + row * 128 + ((k8 * 16) ^ ((row & 7) << 4))) = pk.v;
        }
        // ---- stage B: W[e][k][n] -> Blds[n][k] (transpose via k-gather) ----
#pragma unroll
        for (int c = 0; c < 4; ++c) {
            const int idx = t + c * 256;
            const int n = idx & 127, kc = idx >> 7;           // kc in 0..7
            const float* src = We + (size_t)(kt * 64 + kc * 8) * DDIM + n;
            union { bf16x8 v; unsigned short u[8]; } pk;
#pragma unroll
            for (int j = 0; j < 8; ++j) pk.u[j] = f2bf(src[(size_t)j * DDIM]);
            *(bf16x8*)(Blds + n * 128 + ((kc * 16) ^ ((n & 7) << 4))) = pk.v;
        }
        __syncthreads();

        // ---- compute: 2 x (4x4) MFMA 16x16x32 ----
#pragma unroll
        for (int ks = 0; ks < 2; ++ks) {
            bf16x8 af[4], bf[4];
#pragma unroll
            for (int m = 0; m < 4; ++m) {
                const int row = wr * 64 + m * 16 + l16;
                af[m] = *(const bf16x8*)(Alds + row * 128 + ((ks * 64 + l4 * 16) ^ ((row & 7) << 4)));
            }
#pragma unroll
            for (int n = 0; n < 4; ++n) {
                const int rn = wc * 64 + n * 16 + l16;
                bf[n] = *(const bf16x8*)(Blds + rn * 128 + ((ks * 64 + l4 * 16) ^ ((rn & 7) << 4)));
            }
#pragma unroll
            for (int m = 0; m < 4; ++m)
#pragma unroll
                for (int n = 0; n < 4; ++n)
                    acc[m][n] = __builtin_amdgcn_mfma_f32_16x16x32_bf16(af[m], bf[n], acc[m][n], 0, 0, 0);
        }
        __syncthreads();
    }

    // ---- epilogue: out[b,h] += g * exp(acc + bias) ----
#pragma unroll
    for (int m = 0; m < 4; ++m) {
#pragma unroll
        for (int n = 0; n < 4; ++n) {
#pragma unroll
            for (int j = 0; j < 4; ++j) {
                const int R = wr * 64 + m * 16 + l4 * 4 + j;   // C/D: row=(l>>4)*4+j, col=l&15
                if (row0 + R < cnt) {
                    const int   brow = srow[R];
                    const float g    = sgate[R];
                    const int   h    = nt * 128 + wc * 64 + n * 16 + l16;
                    const float v    = g * __expf(acc[m][n][j] + bias[e * DDIM + h]);
                    unsafeAtomicAdd(out + (size_t)brow * DDIM + h, v);
                }
            }
        }
    }
}

// ---------------------------------------------------------------------------
// Kernel 3: in-place out = log(max(combined, EPS-on-zero))
// ---------------------------------------------------------------------------
__global__ __launch_bounds__(256) void logeps_kernel(float* __restrict__ o, int n4)
{
    const float EPSF = 2.220446049250313e-16f;  // np.finfo(float64).eps
    int i = blockIdx.x * blockDim.x + threadIdx.x;
    const int stride = gridDim.x * blockDim.x;
    float4* p = (float4*)o;
    for (; i < n4; i += stride) {
        float4 v = p[i];
        v.x = __logf(v.x == 0.0f ? EPSF : v.x);
        v.y = __logf(v.y == 0.0f ? EPSF : v.y);
        v.z = __logf(v.z == 0.0f ? EPSF : v.z);
        v.w = __logf(v.w == 0.0f ? EPSF : v.w);
        p[i] = v;
    }
}

// ---------------------------------------------------------------------------
extern "C" void kernel_launch(void* const* d_in, const int* in_sizes, int n_in,
                              void* d_out, int out_size, void* d_ws, size_t ws_size,
                              hipStream_t stream)
{
    const float* x       = (const float*)d_in[0];
    const float* noise   = (const float*)d_in[1];
    const float* w_gate  = (const float*)d_in[2];
    const float* w_noise = (const float*)d_in[3];
    const float* W       = (const float*)d_in[4];
    const float* bias    = (const float*)d_in[5];
    float* out = (float*)d_out;

    char* ws = (char*)d_ws;
    int*   counts   = (int*)ws;                                   // 8 ints
    int*   rowlist  = (int*)(ws + 64);                            // 8 x 8192 ints
    float* gatelist = (float*)(ws + 64 + NEXP * B_ROWS * 4);      // 8 x 8192 floats

    hipMemsetAsync(counts, 0, 64, stream);
    hipMemsetAsync(d_out, 0, (size_t)out_size * sizeof(float), stream);

    gating_kernel<<<B_ROWS / 16, 512, 0, stream>>>(x, noise, w_gate, w_noise,
                                                   counts, rowlist, gatelist);

    dim3 grid(NEXP, B_ROWS / 128, NEXP);   // (nt=8, mt=64 worst case, e=8)
    moe_gemm_kernel<<<grid, 256, 0, stream>>>(x, W, bias, counts, rowlist, gatelist, out);

    logeps_kernel<<<2048, 256, 0, stream>>>(out, out_size / 4);
}

// Round 3
// 368.135 us; speedup vs baseline: 1.3295x; 1.0757x over previous
//
#include <hip/hip_runtime.h>
#include <hip/hip_bf16.h>
#include <math.h>

#define B_ROWS 8192
#define DDIM   1024
#define NEXP   8

typedef __attribute__((ext_vector_type(8))) __bf16 bf16x8;
typedef __attribute__((ext_vector_type(4))) float  f32x4;

__device__ __forceinline__ unsigned short f2bf(float f) {
    // round-to-nearest-even f32 -> bf16
    unsigned u = __builtin_bit_cast(unsigned, f);
    u = (u + 0x7fffu + ((u >> 16) & 1u)) >> 16;
    return (unsigned short)u;
}

// async global->LDS, 16B per lane; LDS dest = wave-uniform base + lane*16
#define GLOAD_LDS16(gptr, lptr)                                                \
    __builtin_amdgcn_global_load_lds(                                          \
        (const __attribute__((address_space(1))) unsigned int*)(gptr),         \
        (__attribute__((address_space(3))) unsigned int*)(lptr), 16, 0, 0)

// ---------------------------------------------------------------------------
// Pre-pass A: x (f32) -> xbf (bf16), 8M elements.
// ---------------------------------------------------------------------------
__global__ __launch_bounds__(256) void xconv_kernel(
    const float* __restrict__ x, __hip_bfloat16* __restrict__ xbf)
{
    int i = blockIdx.x * 256 + threadIdx.x;
    const int stride = gridDim.x * 256;
    const int n8 = B_ROWS * DDIM / 8;
    for (; i < n8; i += stride) {
        const float4 f0 = *(const float4*)(x + (size_t)i * 8);
        const float4 f1 = *(const float4*)(x + (size_t)i * 8 + 4);
        union { bf16x8 v; unsigned short u[8]; } pk;
        pk.u[0] = f2bf(f0.x); pk.u[1] = f2bf(f0.y); pk.u[2] = f2bf(f0.z); pk.u[3] = f2bf(f0.w);
        pk.u[4] = f2bf(f1.x); pk.u[5] = f2bf(f1.y); pk.u[6] = f2bf(f1.z); pk.u[7] = f2bf(f1.w);
        *(bf16x8*)((__hip_bfloat16*)xbf + (size_t)i * 8) = pk.v;
    }
}

// ---------------------------------------------------------------------------
// Pre-pass B: W [e][k][n] f32 -> Wt [e][n][k] bf16 via 64x64 LDS tile.
// ---------------------------------------------------------------------------
__global__ __launch_bounds__(256) void wtrans_kernel(
    const float* __restrict__ W, __hip_bfloat16* __restrict__ Wt)
{
    const int e  = blockIdx.z;
    const int k0 = blockIdx.y * 64;
    const int n0 = blockIdx.x * 64;
    __shared__ float st[64][65];          // +1 pad: bank = (k + n) % 32

    const int t = threadIdx.x;
    {
        const int kk = t >> 4;            // 0..15 per pass
        const int nn = (t & 15) * 4;
#pragma unroll
        for (int p = 0; p < 4; ++p) {
            const int k = p * 16 + kk;
            const float4 v = *(const float4*)(W + (size_t)e * DDIM * DDIM
                                                + (size_t)(k0 + k) * DDIM + n0 + nn);
            st[k][nn + 0] = v.x; st[k][nn + 1] = v.y;
            st[k][nn + 2] = v.z; st[k][nn + 3] = v.w;
        }
    }
    __syncthreads();
    {
        const int wave = t >> 6, lane = t & 63;
        const int nr = lane >> 3, kc = lane & 7;
#pragma unroll
        for (int p = 0; p < 2; ++p) {
            const int n = p * 32 + wave * 8 + nr;
            union { bf16x8 v; unsigned short u[8]; } pk;
#pragma unroll
            for (int j = 0; j < 8; ++j) pk.u[j] = f2bf(st[kc * 8 + j][n]);
            *(bf16x8*)((__hip_bfloat16*)Wt + (size_t)e * DDIM * DDIM
                        + (size_t)(n0 + n) * DDIM + k0 + kc * 8) = pk.v;
        }
    }
}

// ---------------------------------------------------------------------------
// Kernel 1: gating v3. 256 threads, 4 waves; wave owns 4 rows.
// w_gate|w_noise staged once into a 64KB LDS table [k][16] (cols 0-7 clean,
// 8-15 noise). Lane (rs=lane>>4, c=lane&15) accumulates output c of row rs
// over the FULL K in-register: f32 products, f64 accumulation (logit error
// ~4e-8 -> top-k selection matches the f64 numpy reference).
// Per-row top-2 via 8-lane shuffle butterfly (tie -> lower index).
// ---------------------------------------------------------------------------
__global__ __launch_bounds__(256) void gating_kernel(
    const float* __restrict__ x, const float* __restrict__ noise,
    const float* __restrict__ w_gate, const float* __restrict__ w_noise,
    int* __restrict__ counts, int* __restrict__ rowlist, float* __restrict__ gatelist)
{
    __shared__ float wtab[DDIM][16];      // 64KB; bank = (k*16+c)%32 -> broadcast-free

    const int t = threadIdx.x;
    {
        const int k0 = t * 4;
#pragma unroll
        for (int kk = 0; kk < 4; ++kk) {
            const float4 g0 = *(const float4*)(w_gate  + (size_t)(k0 + kk) * NEXP);
            const float4 g1 = *(const float4*)(w_gate  + (size_t)(k0 + kk) * NEXP + 4);
            const float4 n0 = *(const float4*)(w_noise + (size_t)(k0 + kk) * NEXP);
            const float4 n1 = *(const float4*)(w_noise + (size_t)(k0 + kk) * NEXP + 4);
            *(float4*)&wtab[k0 + kk][0]  = g0;
            *(float4*)&wtab[k0 + kk][4]  = g1;
            *(float4*)&wtab[k0 + kk][8]  = n0;
            *(float4*)&wtab[k0 + kk][12] = n1;
        }
    }
    __syncthreads();

    const int wave = t >> 6, lane = t & 63;
    const int rs = lane >> 4, c = lane & 15;
    const int row = (blockIdx.x * 4 + wave) * 4 + rs;

    double acc = 0.0;
    const float* xr = x + (size_t)row * DDIM;
#pragma unroll 4
    for (int k4 = 0; k4 < DDIM / 4; ++k4) {
        const float4 xv = *(const float4*)(xr + k4 * 4);
        acc += (double)(xv.x * wtab[k4 * 4 + 0][c]);
        acc += (double)(xv.y * wtab[k4 * 4 + 1][c]);
        acc += (double)(xv.z * wtab[k4 * 4 + 2][c]);
        acc += (double)(xv.w * wtab[k4 * 4 + 3][c]);
    }

    const double vnoise = __shfl_xor(acc, 8);     // partner column c^8

    double lgv = -1.0e300;
    if (c < 8) {
        const double z  = vnoise;
        const double sp = (z > 30.0) ? z : log1p(exp(z));
        lgv = acc + (double)noise[(size_t)row * NEXP + c] * (sp + 0.01);
    }

    // top-1 butterfly over the 8 logit lanes (offsets 1,2,4 keep c-halves closed)
    double bv = lgv; int bi = c;
#pragma unroll
    for (int off = 1; off <= 4; off <<= 1) {
        const double ov = __shfl_xor(bv, off);
        const int    oi = __shfl_xor(bi, off);
        if (ov > bv || (ov == bv && oi < bi)) { bv = ov; bi = oi; }
    }
    // top-2: mask winner, reduce again
    double b2v = (c == bi) ? -1.0e300 : lgv; int b2i = c;
#pragma unroll
    for (int off = 1; off <= 4; off <<= 1) {
        const double ov = __shfl_xor(b2v, off);
        const int    oi = __shfl_xor(b2i, off);
        if (ov > b2v || (ov == b2v && oi < b2i)) { b2v = ov; b2i = oi; }
    }

    if (c == 0) {
        const double g0 = 1.0 / (1.0 + exp(b2v - bv));
        const double g1 = 1.0 - g0;
        int p0 = atomicAdd(&counts[bi], 1);
        rowlist [bi * B_ROWS + p0] = row;
        gatelist[bi * B_ROWS + p0] = (float)g0;
        int p1 = atomicAdd(&counts[b2i], 1);
        rowlist [b2i * B_ROWS + p1] = row;
        gatelist[b2i * B_ROWS + p1] = (float)g1;
    }
}

// ---------------------------------------------------------------------------
// Kernel 2: grouped expert GEMM from bf16 inputs, m97-structure.
// 128x128 tile, BK=64, 4 waves. Both operands staged via global_load_lds
// (16B/lane, linear LDS dest) with INVERSE-swizzled per-lane SOURCE address
// (rule #21), so ds_read_b128 with byte ^= ((row&7)<<4) is conflict-free.
// Fragment->MFMA->epilogue mapping identical to the round-1-verified kernel.
// ---------------------------------------------------------------------------
__global__ __launch_bounds__(256) void moe_gemm_kernel(
    const __hip_bfloat16* __restrict__ xbf, const __hip_bfloat16* __restrict__ Wt,
    const float* __restrict__ bias,
    const int* __restrict__ counts, const int* __restrict__ rowlist,
    const float* __restrict__ gatelist, float* __restrict__ out)
{
    const int e  = blockIdx.z;
    const int mt = blockIdx.y;
    const int nt = blockIdx.x;
    const int cnt  = counts[e];
    const int row0 = mt * 128;
    if (row0 >= cnt) return;

    __shared__ int   srow[128];
    __shared__ float sgate[128];
    __shared__ __align__(16) unsigned char Alds[128 * 128];  // [row][64 bf16]
    __shared__ __align__(16) unsigned char Blds[128 * 128];  // [n][64 bf16]

    const int t = threadIdx.x;
    if (t < 128) {
        const int r = row0 + t;
        srow[t]  = (r < cnt) ? rowlist[e * B_ROWS + r]  : 0;
        sgate[t] = (r < cnt) ? gatelist[e * B_ROWS + r] : 0.0f;
    }
    __syncthreads();

    const int wave = t >> 6, lane = t & 63;
    const int wr = wave >> 1, wc = wave & 1;
    const int l4 = lane >> 4, l16 = lane & 15;
    const int lrow  = lane >> 3;            // 0..7: row within 8-row stripe
    const int lchunk = (lane & 7) ^ lrow;   // inverse swizzle: slot s holds chunk s^row

    // per-lane byte source bases (constant over kt)
    const char* asrc[4]; const char* bsrc[4];
#pragma unroll
    for (int i = 0; i < 4; ++i) {
        const int r  = wave * 32 + i * 8 + lrow;
        asrc[i] = (const char*)xbf + 2 * ((size_t)srow[r] * DDIM + lchunk * 8);
        const int gn = nt * 128 + wave * 32 + i * 8 + lrow;
        bsrc[i] = (const char*)Wt  + 2 * ((size_t)e * DDIM * DDIM + (size_t)gn * DDIM + lchunk * 8);
    }

    f32x4 acc[4][4];
#pragma unroll
    for (int m = 0; m < 4; ++m)
#pragma unroll
        for (int n = 0; n < 4; ++n) acc[m][n] = (f32x4){0.f, 0.f, 0.f, 0.f};

    for (int kt = 0; kt < DDIM / 64; ++kt) {
        const int koff = kt * 128;  // bytes
#pragma unroll
        for (int i = 0; i < 4; ++i) {
            GLOAD_LDS16(asrc[i] + koff, Alds + (wave * 32 + i * 8) * 128);
            GLOAD_LDS16(bsrc[i] + koff, Blds + (wave * 32 + i * 8) * 128);
        }
        asm volatile("s_waitcnt vmcnt(0)" ::: "memory");
        __syncthreads();

#pragma unroll
        for (int ks = 0; ks < 2; ++ks) {
            bf16x8 af[4], bfr[4];
#pragma unroll
            for (int m = 0; m < 4; ++m) {
                const int row = wr * 64 + m * 16 + l16;
                af[m] = *(const bf16x8*)(Alds + row * 128 + ((ks * 64 + l4 * 16) ^ ((row & 7) << 4)));
            }
#pragma unroll
            for (int n = 0; n < 4; ++n) {
                const int rn = wc * 64 + n * 16 + l16;
                bfr[n] = *(const bf16x8*)(Blds + rn * 128 + ((ks * 64 + l4 * 16) ^ ((rn & 7) << 4)));
            }
#pragma unroll
            for (int m = 0; m < 4; ++m)
#pragma unroll
                for (int n = 0; n < 4; ++n)
                    acc[m][n] = __builtin_amdgcn_mfma_f32_16x16x32_bf16(af[m], bfr[n], acc[m][n], 0, 0, 0);
        }
        __syncthreads();
    }

    // ---- epilogue: out[b,h] += g * exp(acc + bias) ----
#pragma unroll
    for (int m = 0; m < 4; ++m) {
#pragma unroll
        for (int n = 0; n < 4; ++n) {
#pragma unroll
            for (int j = 0; j < 4; ++j) {
                const int R = wr * 64 + m * 16 + l4 * 4 + j;   // C/D: row=(l>>4)*4+j, col=l&15
                if (row0 + R < cnt) {
                    const int   brow = srow[R];
                    const float g    = sgate[R];
                    const int   h    = nt * 128 + wc * 64 + n * 16 + l16;
                    const float v    = g * __expf(acc[m][n][j] + bias[e * DDIM + h]);
                    unsafeAtomicAdd(out + (size_t)brow * DDIM + h, v);
                }
            }
        }
    }
}

// ---------------------------------------------------------------------------
// Kernel 3: in-place out = log(combined, 0 -> EPS)
// ---------------------------------------------------------------------------
__global__ __launch_bounds__(256) void logeps_kernel(float* __restrict__ o, int n4)
{
    const float EPSF = 2.220446049250313e-16f;  // np.finfo(float64).eps
    int i = blockIdx.x * blockDim.x + threadIdx.x;
    const int stride = gridDim.x * blockDim.x;
    float4* p = (float4*)o;
    for (; i < n4; i += stride) {
        float4 v = p[i];
        v.x = __logf(v.x == 0.0f ? EPSF : v.x);
        v.y = __logf(v.y == 0.0f ? EPSF : v.y);
        v.z = __logf(v.z == 0.0f ? EPSF : v.z);
        v.w = __logf(v.w == 0.0f ? EPSF : v.w);
        p[i] = v;
    }
}

// ---------------------------------------------------------------------------
extern "C" void kernel_launch(void* const* d_in, const int* in_sizes, int n_in,
                              void* d_out, int out_size, void* d_ws, size_t ws_size,
                              hipStream_t stream)
{
    const float* x       = (const float*)d_in[0];
    const float* noise   = (const float*)d_in[1];
    const float* w_gate  = (const float*)d_in[2];
    const float* w_noise = (const float*)d_in[3];
    const float* W       = (const float*)d_in[4];
    const float* bias    = (const float*)d_in[5];
    float* out = (float*)d_out;

    char* ws = (char*)d_ws;
    int*   counts   = (int*)ws;                                    // 64 B
    int*   rowlist  = (int*)(ws + 1024);                           // 256 KB
    float* gatelist = (float*)(ws + 1024 + NEXP * B_ROWS * 4);     // 256 KB
    __hip_bfloat16* xbf = (__hip_bfloat16*)(ws + (1u << 20));                  // 16 MB
    __hip_bfloat16* Wt  = (__hip_bfloat16*)(ws + (1u << 20) + (16u << 20));    // 16 MB

    hipMemsetAsync(counts, 0, 64, stream);
    hipMemsetAsync(d_out, 0, (size_t)out_size * sizeof(float), stream);

    xconv_kernel<<<1024, 256, 0, stream>>>(x, xbf);
    wtrans_kernel<<<dim3(16, 16, NEXP), 256, 0, stream>>>(W, Wt);
    gating_kernel<<<B_ROWS / 16, 256, 0, stream>>>(x, noise, w_gate, w_noise,
                                                   counts, rowlist, gatelist);

    dim3 grid(NEXP, B_ROWS / 128, NEXP);
    moe_gemm_kernel<<<grid, 256, 0, stream>>>(xbf, Wt, bias, counts, rowlist, gatelist, out);

    logeps_kernel<<<2048, 256, 0, stream>>>(out, out_size / 4);
}

// Round 4
// 323.537 us; speedup vs baseline: 1.5127x; 1.1378x over previous
//
#include <hip/hip_runtime.h>
#include <hip/hip_bf16.h>
#include <math.h>

#define B_ROWS 8192
#define DDIM   1024
#define NEXP   8

typedef __attribute__((ext_vector_type(8))) __bf16 bf16x8;
typedef __attribute__((ext_vector_type(4))) float  f32x4;

__device__ __forceinline__ unsigned short f2bf(float f) {
    // round-to-nearest-even f32 -> bf16
    unsigned u = __builtin_bit_cast(unsigned, f);
    u = (u + 0x7fffu + ((u >> 16) & 1u)) >> 16;
    return (unsigned short)u;
}

// async global->LDS, 16B per lane; LDS dest = wave-uniform base + lane*16
#define GLOAD_LDS16(gptr, lptr)                                                \
    __builtin_amdgcn_global_load_lds(                                          \
        (const __attribute__((address_space(1))) unsigned int*)(gptr),         \
        (__attribute__((address_space(3))) unsigned int*)(lptr), 16, 0, 0)

// ---------------------------------------------------------------------------
// Pre-pass A: x (f32) -> xbf (bf16), 8M elements.
// ---------------------------------------------------------------------------
__global__ __launch_bounds__(256) void xconv_kernel(
    const float* __restrict__ x, __hip_bfloat16* __restrict__ xbf)
{
    int i = blockIdx.x * 256 + threadIdx.x;
    const int stride = gridDim.x * 256;
    const int n8 = B_ROWS * DDIM / 8;
    for (; i < n8; i += stride) {
        const float4 f0 = *(const float4*)(x + (size_t)i * 8);
        const float4 f1 = *(const float4*)(x + (size_t)i * 8 + 4);
        union { bf16x8 v; unsigned short u[8]; } pk;
        pk.u[0] = f2bf(f0.x); pk.u[1] = f2bf(f0.y); pk.u[2] = f2bf(f0.z); pk.u[3] = f2bf(f0.w);
        pk.u[4] = f2bf(f1.x); pk.u[5] = f2bf(f1.y); pk.u[6] = f2bf(f1.z); pk.u[7] = f2bf(f1.w);
        *(bf16x8*)((__hip_bfloat16*)xbf + (size_t)i * 8) = pk.v;
    }
}

// ---------------------------------------------------------------------------
// Pre-pass B: W [e][k][n] f32 -> Wt [e][n][k] bf16 via 64x64 LDS tile.
// ---------------------------------------------------------------------------
__global__ __launch_bounds__(256) void wtrans_kernel(
    const float* __restrict__ W, __hip_bfloat16* __restrict__ Wt)
{
    const int e  = blockIdx.z;
    const int k0 = blockIdx.y * 64;
    const int n0 = blockIdx.x * 64;
    __shared__ float st[64][65];          // +1 pad: bank = (k + n) % 32

    const int t = threadIdx.x;
    {
        const int kk = t >> 4;            // 0..15 per pass
        const int nn = (t & 15) * 4;
#pragma unroll
        for (int p = 0; p < 4; ++p) {
            const int k = p * 16 + kk;
            const float4 v = *(const float4*)(W + (size_t)e * DDIM * DDIM
                                                + (size_t)(k0 + k) * DDIM + n0 + nn);
            st[k][nn + 0] = v.x; st[k][nn + 1] = v.y;
            st[k][nn + 2] = v.z; st[k][nn + 3] = v.w;
        }
    }
    __syncthreads();
    {
        const int wave = t >> 6, lane = t & 63;
        const int nr = lane >> 3, kc = lane & 7;
#pragma unroll
        for (int p = 0; p < 2; ++p) {
            const int n = p * 32 + wave * 8 + nr;
            union { bf16x8 v; unsigned short u[8]; } pk;
#pragma unroll
            for (int j = 0; j < 8; ++j) pk.u[j] = f2bf(st[kc * 8 + j][n]);
            *(bf16x8*)((__hip_bfloat16*)Wt + (size_t)e * DDIM * DDIM
                        + (size_t)(n0 + n) * DDIM + k0 + kc * 8) = pk.v;
        }
    }
}

// ---------------------------------------------------------------------------
// Kernel 1: gating v3 (unchanged math) + rank bit in rowlist.
// Lane (rs=lane>>4, c=lane&15) accumulates output c of row rs over full K:
// f32 products, f64 accumulation -> selection matches f64 numpy reference.
// rowlist entry = row | (rank<<31): rank0 = top-1 expert, rank1 = top-2.
// ---------------------------------------------------------------------------
__global__ __launch_bounds__(256) void gating_kernel(
    const float* __restrict__ x, const float* __restrict__ noise,
    const float* __restrict__ w_gate, const float* __restrict__ w_noise,
    int* __restrict__ counts, int* __restrict__ rowlist, float* __restrict__ gatelist)
{
    __shared__ float wtab[DDIM][16];      // 64KB

    const int t = threadIdx.x;
    {
        const int k0 = t * 4;
#pragma unroll
        for (int kk = 0; kk < 4; ++kk) {
            const float4 g0 = *(const float4*)(w_gate  + (size_t)(k0 + kk) * NEXP);
            const float4 g1 = *(const float4*)(w_gate  + (size_t)(k0 + kk) * NEXP + 4);
            const float4 n0 = *(const float4*)(w_noise + (size_t)(k0 + kk) * NEXP);
            const float4 n1 = *(const float4*)(w_noise + (size_t)(k0 + kk) * NEXP + 4);
            *(float4*)&wtab[k0 + kk][0]  = g0;
            *(float4*)&wtab[k0 + kk][4]  = g1;
            *(float4*)&wtab[k0 + kk][8]  = n0;
            *(float4*)&wtab[k0 + kk][12] = n1;
        }
    }
    __syncthreads();

    const int wave = t >> 6, lane = t & 63;
    const int rs = lane >> 4, c = lane & 15;
    const int row = (blockIdx.x * 4 + wave) * 4 + rs;

    double acc = 0.0;
    const float* xr = x + (size_t)row * DDIM;
#pragma unroll 4
    for (int k4 = 0; k4 < DDIM / 4; ++k4) {
        const float4 xv = *(const float4*)(xr + k4 * 4);
        acc += (double)(xv.x * wtab[k4 * 4 + 0][c]);
        acc += (double)(xv.y * wtab[k4 * 4 + 1][c]);
        acc += (double)(xv.z * wtab[k4 * 4 + 2][c]);
        acc += (double)(xv.w * wtab[k4 * 4 + 3][c]);
    }

    const double vnoise = __shfl_xor(acc, 8);     // partner column c^8

    double lgv = -1.0e300;
    if (c < 8) {
        const double z  = vnoise;
        const double sp = (z > 30.0) ? z : log1p(exp(z));
        lgv = acc + (double)noise[(size_t)row * NEXP + c] * (sp + 0.01);
    }

    // top-1 butterfly over the 8 logit lanes
    double bv = lgv; int bi = c;
#pragma unroll
    for (int off = 1; off <= 4; off <<= 1) {
        const double ov = __shfl_xor(bv, off);
        const int    oi = __shfl_xor(bi, off);
        if (ov > bv || (ov == bv && oi < bi)) { bv = ov; bi = oi; }
    }
    // top-2: mask winner, reduce again
    double b2v = (c == bi) ? -1.0e300 : lgv; int b2i = c;
#pragma unroll
    for (int off = 1; off <= 4; off <<= 1) {
        const double ov = __shfl_xor(b2v, off);
        const int    oi = __shfl_xor(b2i, off);
        if (ov > b2v || (ov == b2v && oi < b2i)) { b2v = ov; b2i = oi; }
    }

    if (c == 0) {
        const double g0 = 1.0 / (1.0 + exp(b2v - bv));
        const double g1 = 1.0 - g0;
        int p0 = atomicAdd(&counts[bi], 1);
        rowlist [bi * B_ROWS + p0] = row;                              // rank 0
        gatelist[bi * B_ROWS + p0] = (float)g0;
        int p1 = atomicAdd(&counts[b2i], 1);
        rowlist [b2i * B_ROWS + p1] = (int)((unsigned)row | 0x80000000u); // rank 1
        gatelist[b2i * B_ROWS + p1] = (float)g1;
    }
}

// ---------------------------------------------------------------------------
// Kernel 2: grouped expert GEMM, m97-structure, 128x128 tile, BK=64.
// Grid = (nt, e, mt): consecutive dispatch ids cover all experts at one mt
// -> resident window is fully active (fixes 1-block/CU starvation), and
// id%8 == nt keeps B-panel (same e,nt) reuse on one XCD.
// Epilogue: rank0 rows -> plain store to out, rank1 rows -> out2 (no atomics;
// every row appears exactly once per rank, so both buffers are fully written).
// ---------------------------------------------------------------------------
__global__ __launch_bounds__(256) void moe_gemm_kernel(
    const __hip_bfloat16* __restrict__ xbf, const __hip_bfloat16* __restrict__ Wt,
    const float* __restrict__ bias,
    const int* __restrict__ counts, const int* __restrict__ rowlist,
    const float* __restrict__ gatelist, float* __restrict__ out, float* __restrict__ out2)
{
    const int nt = blockIdx.x;
    const int e  = blockIdx.y;
    const int mt = blockIdx.z;
    const int cnt  = counts[e];
    const int row0 = mt * 128;
    if (row0 >= cnt) return;

    __shared__ int   srow[128];
    __shared__ unsigned char srank[128];
    __shared__ float sgate[128];
    __shared__ __align__(16) unsigned char Alds[128 * 128];  // [row][64 bf16]
    __shared__ __align__(16) unsigned char Blds[128 * 128];  // [n][64 bf16]

    const int t = threadIdx.x;
    if (t < 128) {
        const int r = row0 + t;
        const unsigned er = (r < cnt) ? (unsigned)rowlist[e * B_ROWS + r] : 0u;
        srow[t]  = (int)(er & 0x7fffffffu);
        srank[t] = (unsigned char)(er >> 31);
        sgate[t] = (r < cnt) ? gatelist[e * B_ROWS + r] : 0.0f;
    }
    __syncthreads();

    const int wave = t >> 6, lane = t & 63;
    const int wr = wave >> 1, wc = wave & 1;
    const int l4 = lane >> 4, l16 = lane & 15;
    const int lrow  = lane >> 3;            // 0..7: row within 8-row stripe
    const int lchunk = (lane & 7) ^ lrow;   // inverse swizzle: slot s holds chunk s^row

    // per-lane byte source bases (constant over kt)
    const char* asrc[4]; const char* bsrc[4];
#pragma unroll
    for (int i = 0; i < 4; ++i) {
        const int r  = wave * 32 + i * 8 + lrow;
        asrc[i] = (const char*)xbf + 2 * ((size_t)srow[r] * DDIM + lchunk * 8);
        const int gn = nt * 128 + wave * 32 + i * 8 + lrow;
        bsrc[i] = (const char*)Wt  + 2 * ((size_t)e * DDIM * DDIM + (size_t)gn * DDIM + lchunk * 8);
    }

    f32x4 acc[4][4];
#pragma unroll
    for (int m = 0; m < 4; ++m)
#pragma unroll
        for (int n = 0; n < 4; ++n) acc[m][n] = (f32x4){0.f, 0.f, 0.f, 0.f};

    for (int kt = 0; kt < DDIM / 64; ++kt) {
        const int koff = kt * 128;  // bytes
#pragma unroll
        for (int i = 0; i < 4; ++i) {
            GLOAD_LDS16(asrc[i] + koff, Alds + (wave * 32 + i * 8) * 128);
            GLOAD_LDS16(bsrc[i] + koff, Blds + (wave * 32 + i * 8) * 128);
        }
        asm volatile("s_waitcnt vmcnt(0)" ::: "memory");
        __syncthreads();

#pragma unroll
        for (int ks = 0; ks < 2; ++ks) {
            bf16x8 af[4], bfr[4];
#pragma unroll
            for (int m = 0; m < 4; ++m) {
                const int row = wr * 64 + m * 16 + l16;
                af[m] = *(const bf16x8*)(Alds + row * 128 + ((ks * 64 + l4 * 16) ^ ((row & 7) << 4)));
            }
#pragma unroll
            for (int n = 0; n < 4; ++n) {
                const int rn = wc * 64 + n * 16 + l16;
                bfr[n] = *(const bf16x8*)(Blds + rn * 128 + ((ks * 64 + l4 * 16) ^ ((rn & 7) << 4)));
            }
#pragma unroll
            for (int m = 0; m < 4; ++m)
#pragma unroll
                for (int n = 0; n < 4; ++n)
                    acc[m][n] = __builtin_amdgcn_mfma_f32_16x16x32_bf16(af[m], bfr[n], acc[m][n], 0, 0, 0);
        }
        __syncthreads();
    }

    // ---- epilogue: dst[b,h] = g * exp(acc + bias), dst = rank ? out2 : out ----
#pragma unroll
    for (int m = 0; m < 4; ++m) {
#pragma unroll
        for (int n = 0; n < 4; ++n) {
#pragma unroll
            for (int j = 0; j < 4; ++j) {
                const int R = wr * 64 + m * 16 + l4 * 4 + j;   // C/D: row=(l>>4)*4+j, col=l&15
                if (row0 + R < cnt) {
                    const int   brow = srow[R];
                    const float g    = sgate[R];
                    const int   h    = nt * 128 + wc * 64 + n * 16 + l16;
                    const float v    = g * __expf(acc[m][n][j] + bias[e * DDIM + h]);
                    float* dst = srank[R] ? out2 : out;
                    dst[(size_t)brow * DDIM + h] = v;
                }
            }
        }
    }
}

// ---------------------------------------------------------------------------
// Kernel 3: out = log(out + out2), 0 -> EPS
// ---------------------------------------------------------------------------
__global__ __launch_bounds__(256) void logeps_kernel(
    float* __restrict__ o, const float* __restrict__ o2, int n4)
{
    const float EPSF = 2.220446049250313e-16f;  // np.finfo(float64).eps
    int i = blockIdx.x * blockDim.x + threadIdx.x;
    const int stride = gridDim.x * blockDim.x;
    float4* p = (float4*)o;
    const float4* q = (const float4*)o2;
    for (; i < n4; i += stride) {
        float4 a = p[i];
        const float4 b = q[i];
        a.x += b.x; a.y += b.y; a.z += b.z; a.w += b.w;
        a.x = __logf(a.x == 0.0f ? EPSF : a.x);
        a.y = __logf(a.y == 0.0f ? EPSF : a.y);
        a.z = __logf(a.z == 0.0f ? EPSF : a.z);
        a.w = __logf(a.w == 0.0f ? EPSF : a.w);
        p[i] = a;
    }
}

// ---------------------------------------------------------------------------
extern "C" void kernel_launch(void* const* d_in, const int* in_sizes, int n_in,
                              void* d_out, int out_size, void* d_ws, size_t ws_size,
                              hipStream_t stream)
{
    const float* x       = (const float*)d_in[0];
    const float* noise   = (const float*)d_in[1];
    const float* w_gate  = (const float*)d_in[2];
    const float* w_noise = (const float*)d_in[3];
    const float* W       = (const float*)d_in[4];
    const float* bias    = (const float*)d_in[5];
    float* out = (float*)d_out;

    char* ws = (char*)d_ws;
    int*   counts   = (int*)ws;                                    // 64 B
    int*   rowlist  = (int*)(ws + 1024);                           // 256 KB
    float* gatelist = (float*)(ws + 1024 + NEXP * B_ROWS * 4);     // 256 KB
    __hip_bfloat16* xbf = (__hip_bfloat16*)(ws + (1u << 20));                  // 16 MB
    __hip_bfloat16* Wt  = (__hip_bfloat16*)(ws + (1u << 20) + (16u << 20));    // 16 MB
    float* out2 = (float*)(ws + (1u << 20) + (32u << 20));                     // 32 MB

    hipMemsetAsync(counts, 0, 64, stream);

    xconv_kernel<<<1024, 256, 0, stream>>>(x, xbf);
    wtrans_kernel<<<dim3(16, 16, NEXP), 256, 0, stream>>>(W, Wt);
    gating_kernel<<<B_ROWS / 16, 256, 0, stream>>>(x, noise, w_gate, w_noise,
                                                   counts, rowlist, gatelist);

    dim3 grid(NEXP /*nt*/, NEXP /*e*/, B_ROWS / 128 /*mt*/);
    moe_gemm_kernel<<<grid, 256, 0, stream>>>(xbf, Wt, bias, counts, rowlist, gatelist,
                                              out, out2);

    logeps_kernel<<<2048, 256, 0, stream>>>(out, out2, out_size / 4);
}